// Round 2
// baseline (716.011 us; speedup 1.0000x reference)
//
#include <hip/hip_runtime.h>

#define NN 100000
#define NE 1600000
#define NF 512
#define NH 128
#define NC 64

typedef __attribute__((ext_vector_type(8))) short bf16x8;
typedef __attribute__((ext_vector_type(4))) float f32x4;

static __device__ __forceinline__ unsigned short f2bf(float f) {
  unsigned int u = __float_as_uint(f);
  u += 0x7fffu + ((u >> 16) & 1u);   // RNE
  return (unsigned short)(u >> 16);
}
static __device__ __forceinline__ float bf2f(unsigned short s) {
  return __uint_as_float(((unsigned int)s) << 16);
}

// ---------------- misc small kernels ----------------
__global__ void k_zero(int* __restrict__ p, int n) {
  int i = blockIdx.x * 256 + threadIdx.x;
  if (i < n) p[i] = 0;
}

// W1 [512][128] f32 -> W1t [128][512] bf16 ; W2 [128][64] f32 -> W2t [64][128] bf16
__global__ void k_convw(const float* __restrict__ W1, const float* __restrict__ W2,
                        unsigned short* __restrict__ W1t, unsigned short* __restrict__ W2t) {
  int i = blockIdx.x * 256 + threadIdx.x;
  if (i < NF * NH) {
    int k = i / NH, n = i % NH;
    W1t[n * NF + k] = f2bf(W1[i]);
  }
  int j = i - NF * NH;
  if (j >= 0 && j < NH * NC) {
    int k = j / NC, n = j % NC;
    W2t[n * NH + k] = f2bf(W2[j]);
  }
}

// ---------------- CSR build ----------------
// edge_index is int32 on device (harness materializes integer inputs as int32):
// ei[0..NE) = src, ei[NE..2NE) = dst.
__global__ void k_count(const int* __restrict__ ei, int* __restrict__ counts) {
  int e = blockIdx.x * 256 + threadIdx.x;
  if (e < NE) atomicAdd(&counts[ei[NE + e]], 1);
}

__global__ void k_scan1(const int* __restrict__ counts, int* __restrict__ partials) {
  __shared__ int sd[256];
  int t = threadIdx.x;
  int base = blockIdx.x * 1024 + t * 4;
  int s = 0;
#pragma unroll
  for (int j = 0; j < 4; ++j) { int i = base + j; if (i < NN) s += counts[i]; }
  sd[t] = s; __syncthreads();
  for (int o = 128; o > 0; o >>= 1) { if (t < o) sd[t] += sd[t + o]; __syncthreads(); }
  if (t == 0) partials[blockIdx.x] = sd[0];
}

__global__ void k_scan2(int* __restrict__ partials, int nb) {
  if (threadIdx.x == 0 && blockIdx.x == 0) {
    int run = 0;
    for (int i = 0; i < nb; ++i) { int v = partials[i]; partials[i] = run; run += v; }
  }
}

__global__ void k_scan3(const int* __restrict__ counts, const int* __restrict__ partials,
                        int* __restrict__ rowptr, int* __restrict__ offs) {
  __shared__ int sd[256];
  int t = threadIdx.x;
  int base = blockIdx.x * 1024 + t * 4;
  int v[4]; int s = 0;
#pragma unroll
  for (int j = 0; j < 4; ++j) { int i = base + j; v[j] = (i < NN) ? counts[i] : 0; s += v[j]; }
  sd[t] = s; __syncthreads();
  for (int o = 1; o < 256; o <<= 1) {
    int y = (t >= o) ? sd[t - o] : 0;
    __syncthreads();
    sd[t] += y;
    __syncthreads();
  }
  int run = partials[blockIdx.x] + sd[t] - s;  // exclusive prefix
#pragma unroll
  for (int j = 0; j < 4; ++j) {
    int i = base + j;
    if (i < NN) { rowptr[i] = run; offs[i] = run; run += v[j]; }
  }
  if (t == 0 && blockIdx.x == 0) rowptr[NN] = NE;
}

__global__ void k_scatter(const int* __restrict__ ei, const float* __restrict__ ew,
                          int* __restrict__ offs, int* __restrict__ ssrc, float* __restrict__ sw) {
  int e = blockIdx.x * 256 + threadIdx.x;
  if (e < NE) {
    int d = ei[NE + e];
    int pos = atomicAdd(&offs[d], 1);
    ssrc[pos] = ei[e];
    sw[pos] = ew[e];
  }
}

// ---------------- GEMM1: h[NN][NH] bf16 = x[NN][NF] f32 @ W1 ----------------
__global__ __launch_bounds__(256) void k_gemm1(const float* __restrict__ x,
                                               const unsigned short* __restrict__ W1t,
                                               unsigned short* __restrict__ h) {
  __shared__ __align__(16) unsigned short As[128][72];  // [m][k], +8 pad
  __shared__ __align__(16) unsigned short Bs[128][72];  // [n][k], +8 pad
  int t = threadIdx.x;
  int rowBase = blockIdx.x * 128;
  int wave = t >> 6, lane = t & 63;
  int wm = (wave & 1) * 64, wn = (wave >> 1) * 64;
  int lrow = lane & 15, quad = lane >> 4;

  f32x4 acc[4][4];
#pragma unroll
  for (int i = 0; i < 4; ++i)
#pragma unroll
    for (int j = 0; j < 4; ++j) acc[i][j] = (f32x4){0.f, 0.f, 0.f, 0.f};

  for (int k0 = 0; k0 < NF; k0 += 64) {
#pragma unroll
    for (int i = 0; i < 8; ++i) {           // stage A: 128x64 f32 -> bf16
      int idx = t + i * 256;
      int r = idx >> 4, c4 = idx & 15;
      int row = rowBase + r; if (row >= NN) row = NN - 1;
      const float4 v = *(const float4*)(x + (size_t)row * NF + k0 + c4 * 4);
      ushort4 sv;
      sv.x = f2bf(v.x); sv.y = f2bf(v.y); sv.z = f2bf(v.z); sv.w = f2bf(v.w);
      *(ushort4*)(&As[r][c4 * 4]) = sv;
    }
#pragma unroll
    for (int i = 0; i < 8; ++i) {           // stage B: 128x64 bf16
      int idx = t + i * 256;
      int n = idx >> 4, c4 = idx & 15;
      *(ushort4*)(&Bs[n][c4 * 4]) = *(const ushort4*)(W1t + n * NF + k0 + c4 * 4);
    }
    __syncthreads();
#pragma unroll
    for (int ks = 0; ks < 64; ks += 32) {
      bf16x8 a[4], b[4];
#pragma unroll
      for (int mt = 0; mt < 4; ++mt) a[mt] = *(const bf16x8*)(&As[wm + mt * 16 + lrow][ks + quad * 8]);
#pragma unroll
      for (int nt = 0; nt < 4; ++nt) b[nt] = *(const bf16x8*)(&Bs[wn + nt * 16 + lrow][ks + quad * 8]);
#pragma unroll
      for (int mt = 0; mt < 4; ++mt)
#pragma unroll
        for (int nt = 0; nt < 4; ++nt)
          acc[mt][nt] = __builtin_amdgcn_mfma_f32_16x16x32_bf16(a[mt], b[nt], acc[mt][nt], 0, 0, 0);
    }
    __syncthreads();
  }
#pragma unroll
  for (int mt = 0; mt < 4; ++mt)
#pragma unroll
    for (int nt = 0; nt < 4; ++nt)
#pragma unroll
      for (int r = 0; r < 4; ++r) {
        int row = rowBase + wm + mt * 16 + quad * 4 + r;
        if (row < NN) {
          int col = wn + nt * 16 + lrow;
          h[(size_t)row * NH + col] = f2bf(acc[mt][nt][r]);
        }
      }
}

// ---------------- GEMM2: h3[NN][NC] bf16 = h2[NN][NH] bf16 @ W2 ----------------
__global__ __launch_bounds__(256) void k_gemm2(const unsigned short* __restrict__ h2,
                                               const unsigned short* __restrict__ W2t,
                                               unsigned short* __restrict__ h3) {
  __shared__ __align__(16) unsigned short As[256][72];
  __shared__ __align__(16) unsigned short Bs[64][72];
  int t = threadIdx.x;
  int rowBase = blockIdx.x * 256;
  int wave = t >> 6, lane = t & 63;
  int wm = wave * 64;
  int lrow = lane & 15, quad = lane >> 4;

  f32x4 acc[4][4];
#pragma unroll
  for (int i = 0; i < 4; ++i)
#pragma unroll
    for (int j = 0; j < 4; ++j) acc[i][j] = (f32x4){0.f, 0.f, 0.f, 0.f};

  for (int k0 = 0; k0 < NH; k0 += 64) {
#pragma unroll
    for (int i = 0; i < 16; ++i) {          // stage A: 256x64 bf16
      int idx = t + i * 256;
      int r = idx >> 4, c4 = idx & 15;
      int row = rowBase + r; if (row >= NN) row = NN - 1;
      *(ushort4*)(&As[r][c4 * 4]) = *(const ushort4*)(h2 + (size_t)row * NH + k0 + c4 * 4);
    }
#pragma unroll
    for (int i = 0; i < 4; ++i) {           // stage B: 64x64 bf16
      int idx = t + i * 256;
      int n = idx >> 4, c4 = idx & 15;
      *(ushort4*)(&Bs[n][c4 * 4]) = *(const ushort4*)(W2t + n * NH + k0 + c4 * 4);
    }
    __syncthreads();
#pragma unroll
    for (int ks = 0; ks < 64; ks += 32) {
      bf16x8 a[4], b[4];
#pragma unroll
      for (int mt = 0; mt < 4; ++mt) a[mt] = *(const bf16x8*)(&As[wm + mt * 16 + lrow][ks + quad * 8]);
#pragma unroll
      for (int nt = 0; nt < 4; ++nt) b[nt] = *(const bf16x8*)(&Bs[nt * 16 + lrow][ks + quad * 8]);
#pragma unroll
      for (int mt = 0; mt < 4; ++mt)
#pragma unroll
        for (int nt = 0; nt < 4; ++nt)
          acc[mt][nt] = __builtin_amdgcn_mfma_f32_16x16x32_bf16(a[mt], b[nt], acc[mt][nt], 0, 0, 0);
    }
    __syncthreads();
  }
#pragma unroll
  for (int mt = 0; mt < 4; ++mt)
#pragma unroll
    for (int nt = 0; nt < 4; ++nt)
#pragma unroll
      for (int r = 0; r < 4; ++r) {
        int row = rowBase + wm + mt * 16 + quad * 4 + r;
        if (row < NN) {
          int col = nt * 16 + lrow;
          h3[(size_t)row * NC + col] = f2bf(acc[mt][nt][r]);
        }
      }
}

// ---------------- propagate 1: h2 = relu(seg_sum(w * h[src]) + b1), D=128 ----------------
__global__ __launch_bounds__(256) void k_prop1(const int* __restrict__ rowptr,
                                               const int* __restrict__ ssrc,
                                               const float* __restrict__ sw,
                                               const unsigned short* __restrict__ h,
                                               const float* __restrict__ b1,
                                               unsigned short* __restrict__ h2) {
  int node = blockIdx.x * 4 + (threadIdx.x >> 6);
  int lane = threadIdx.x & 63;
  int e0 = rowptr[node], e1 = rowptr[node + 1];
  float acc0 = 0.f, acc1 = 0.f;
  for (int e = e0; e < e1; e += 64) {
    int cnt = e1 - e; if (cnt > 64) cnt = 64;
    int s = 0; float wv = 0.f;
    if (lane < cnt) { s = ssrc[e + lane]; wv = sw[e + lane]; }
    for (int j = 0; j < cnt; ++j) {
      int sj = __shfl(s, j);
      float wj = __shfl(wv, j);
      unsigned int hv = *(const unsigned int*)(h + (size_t)sj * NH + lane * 2);
      acc0 += wj * bf2f((unsigned short)(hv & 0xffffu));
      acc1 += wj * bf2f((unsigned short)(hv >> 16));
    }
  }
  float o0 = fmaxf(acc0 + b1[lane * 2], 0.f);
  float o1 = fmaxf(acc1 + b1[lane * 2 + 1], 0.f);
  unsigned int packed = ((unsigned int)f2bf(o1) << 16) | (unsigned int)f2bf(o0);
  *(unsigned int*)(h2 + (size_t)node * NH + lane * 2) = packed;
}

// ---------------- propagate 2: out = seg_sum(w * h3[src]) + b2, D=64 ----------------
__global__ __launch_bounds__(256) void k_prop2(const int* __restrict__ rowptr,
                                               const int* __restrict__ ssrc,
                                               const float* __restrict__ sw,
                                               const unsigned short* __restrict__ h3,
                                               const float* __restrict__ b2,
                                               float* __restrict__ out) {
  int node = blockIdx.x * 4 + (threadIdx.x >> 6);
  int lane = threadIdx.x & 63;
  int e0 = rowptr[node], e1 = rowptr[node + 1];
  float acc = 0.f;
  for (int e = e0; e < e1; e += 64) {
    int cnt = e1 - e; if (cnt > 64) cnt = 64;
    int s = 0; float wv = 0.f;
    if (lane < cnt) { s = ssrc[e + lane]; wv = sw[e + lane]; }
    for (int j = 0; j < cnt; ++j) {
      int sj = __shfl(s, j);
      float wj = __shfl(wv, j);
      acc += wj * bf2f(h3[(size_t)sj * NC + lane]);
    }
  }
  out[(size_t)node * NC + lane] = acc + b2[lane];
}

extern "C" void kernel_launch(void* const* d_in, const int* in_sizes, int n_in,
                              void* d_out, int out_size, void* d_ws, size_t ws_size,
                              hipStream_t stream) {
  const float* x = (const float*)d_in[0];
  const int* ei = (const int*)d_in[1];   // int32 on device (harness convention)
  const float* ew = (const float*)d_in[2];
  const float* W1 = (const float*)d_in[3];
  const float* b1 = (const float*)d_in[4];
  const float* W2 = (const float*)d_in[5];
  const float* b2 = (const float*)d_in[6];
  float* out = (float*)d_out;

  char* ws = (char*)d_ws;
  size_t off = 0;
  auto alloc = [&](size_t bytes) {
    char* p = ws + off;
    off = (off + bytes + 255) & ~(size_t)255;
    return p;
  };
  unsigned short* W1t = (unsigned short*)alloc((size_t)NF * NH * 2);
  unsigned short* W2t = (unsigned short*)alloc((size_t)NH * NC * 2);
  unsigned short* h   = (unsigned short*)alloc((size_t)NN * NH * 2);
  unsigned short* h2  = (unsigned short*)alloc((size_t)NN * NH * 2);
  unsigned short* h3  = h;  // h dead after prop1; alias to save ws
  int* rowptr   = (int*)alloc((size_t)(NN + 1) * 4);
  int* offs     = (int*)alloc((size_t)NN * 4);
  int* counts   = (int*)alloc((size_t)NN * 4);
  int* partials = (int*)alloc(4096);
  int* ssrc     = (int*)alloc((size_t)NE * 4);
  float* sw     = (float*)alloc((size_t)NE * 4);

  const int NB = (NN + 1023) / 1024;  // 98

  k_zero<<<(NN + 255) / 256, 256, 0, stream>>>(counts, NN);
  k_convw<<<(NF * NH + NH * NC + 255) / 256, 256, 0, stream>>>(W1, W2, W1t, W2t);
  k_count<<<(NE + 255) / 256, 256, 0, stream>>>(ei, counts);
  k_gemm1<<<(NN + 127) / 128, 256, 0, stream>>>(x, W1t, h);
  k_scan1<<<NB, 256, 0, stream>>>(counts, partials);
  k_scan2<<<1, 64, 0, stream>>>(partials, NB);
  k_scan3<<<NB, 256, 0, stream>>>(counts, partials, rowptr, offs);
  k_scatter<<<(NE + 255) / 256, 256, 0, stream>>>(ei, ew, offs, ssrc, sw);
  k_prop1<<<NN / 4, 256, 0, stream>>>(rowptr, ssrc, sw, h, b1, h2);
  k_gemm2<<<(NN + 255) / 256, 256, 0, stream>>>(h2, W2t, h3);
  k_prop2<<<NN / 4, 256, 0, stream>>>(rowptr, ssrc, sw, h3, b2, out);
}

// Round 3
// 637.064 us; speedup vs baseline: 1.1239x; 1.1239x over previous
//
#include <hip/hip_runtime.h>

#define NN 100000
#define NE 1600000
#define NF 512
#define NH 128
#define NC 64

typedef __attribute__((ext_vector_type(8))) short bf16x8;
typedef __attribute__((ext_vector_type(4))) float f32x4;

static __device__ __forceinline__ unsigned short f2bf(float f) {
  unsigned int u = __float_as_uint(f);
  u += 0x7fffu + ((u >> 16) & 1u);   // RNE
  return (unsigned short)(u >> 16);
}
static __device__ __forceinline__ float bf2f(unsigned short s) {
  return __uint_as_float(((unsigned int)s) << 16);
}

// ---------------- init: zero counts + convert/transpose weights ----------------
__global__ void k_init(const float* __restrict__ W1, const float* __restrict__ W2,
                       unsigned short* __restrict__ W1t, unsigned short* __restrict__ W2t,
                       int* __restrict__ counts) {
  int i = blockIdx.x * 256 + threadIdx.x;
  if (i < NN) counts[i] = 0;
  if (i < NF * NH) {
    int k = i / NH, n = i % NH;
    W1t[n * NF + k] = f2bf(W1[i]);
  }
  int j = i - NF * NH;
  if (j >= 0 && j < NH * NC) {
    int k = j / NC, n = j % NC;
    W2t[n * NH + k] = f2bf(W2[j]);
  }
}

// ---------------- CSR build (edge_index is int32 on device) ----------------
__global__ void k_count(const int* __restrict__ ei, int* __restrict__ counts) {
  int e = blockIdx.x * 256 + threadIdx.x;
  if (e < NE) atomicAdd(&counts[ei[NE + e]], 1);
}

__global__ void k_scan1(const int* __restrict__ counts, int* __restrict__ partials) {
  __shared__ int sd[256];
  int t = threadIdx.x;
  int base = blockIdx.x * 1024 + t * 4;
  int s = 0;
#pragma unroll
  for (int j = 0; j < 4; ++j) { int i = base + j; if (i < NN) s += counts[i]; }
  sd[t] = s; __syncthreads();
  for (int o = 128; o > 0; o >>= 1) { if (t < o) sd[t] += sd[t + o]; __syncthreads(); }
  if (t == 0) partials[blockIdx.x] = sd[0];
}

// parallel exclusive scan of <=128 partials (was single-threaded: ~98 serial L2 RTs)
__global__ void k_scan2(int* __restrict__ partials, int nb) {
  __shared__ int sd[128];
  int t = threadIdx.x;
  int v = (t < nb) ? partials[t] : 0;
  sd[t] = v; __syncthreads();
  for (int o = 1; o < 128; o <<= 1) {
    int y = (t >= o) ? sd[t - o] : 0;
    __syncthreads();
    sd[t] += y;
    __syncthreads();
  }
  if (t < nb) partials[t] = sd[t] - v;  // exclusive
}

__global__ void k_scan3(const int* __restrict__ counts, const int* __restrict__ partials,
                        int* __restrict__ rowptr, int* __restrict__ offs) {
  __shared__ int sd[256];
  int t = threadIdx.x;
  int base = blockIdx.x * 1024 + t * 4;
  int v[4]; int s = 0;
#pragma unroll
  for (int j = 0; j < 4; ++j) { int i = base + j; v[j] = (i < NN) ? counts[i] : 0; s += v[j]; }
  sd[t] = s; __syncthreads();
  for (int o = 1; o < 256; o <<= 1) {
    int y = (t >= o) ? sd[t - o] : 0;
    __syncthreads();
    sd[t] += y;
    __syncthreads();
  }
  int run = partials[blockIdx.x] + sd[t] - s;  // exclusive prefix
#pragma unroll
  for (int j = 0; j < 4; ++j) {
    int i = base + j;
    if (i < NN) { rowptr[i] = run; offs[i] = run; run += v[j]; }
  }
  if (t == 0 && blockIdx.x == 0) rowptr[NN] = NE;
}

// one 8 B store per edge (packed src + weight-bits) instead of two 4 B stores
__global__ void k_scatter(const int* __restrict__ ei, const float* __restrict__ ew,
                          int* __restrict__ offs, int2* __restrict__ sedge) {
  int e = blockIdx.x * 256 + threadIdx.x;
  if (e < NE) {
    int d = ei[NE + e];
    int pos = atomicAdd(&offs[d], 1);
    sedge[pos] = make_int2(ei[e], __float_as_int(ew[e]));
  }
}

// ---------------- GEMM1: h[NN][NH] bf16 = x[NN][NF] f32 @ W1 ----------------
__global__ __launch_bounds__(256) void k_gemm1(const float* __restrict__ x,
                                               const unsigned short* __restrict__ W1t,
                                               unsigned short* __restrict__ h) {
  __shared__ __align__(16) unsigned short As[128][72];  // [m][k], +8 pad
  __shared__ __align__(16) unsigned short Bs[128][72];  // [n][k], +8 pad
  int t = threadIdx.x;
  int rowBase = blockIdx.x * 128;
  int wave = t >> 6, lane = t & 63;
  int wm = (wave & 1) * 64, wn = (wave >> 1) * 64;
  int lrow = lane & 15, quad = lane >> 4;

  f32x4 acc[4][4];
#pragma unroll
  for (int i = 0; i < 4; ++i)
#pragma unroll
    for (int j = 0; j < 4; ++j) acc[i][j] = (f32x4){0.f, 0.f, 0.f, 0.f};

  for (int k0 = 0; k0 < NF; k0 += 64) {
#pragma unroll
    for (int i = 0; i < 8; ++i) {           // stage A: 128x64 f32 -> bf16
      int idx = t + i * 256;
      int r = idx >> 4, c4 = idx & 15;
      int row = rowBase + r; if (row >= NN) row = NN - 1;
      const float4 v = *(const float4*)(x + (size_t)row * NF + k0 + c4 * 4);
      ushort4 sv;
      sv.x = f2bf(v.x); sv.y = f2bf(v.y); sv.z = f2bf(v.z); sv.w = f2bf(v.w);
      *(ushort4*)(&As[r][c4 * 4]) = sv;
    }
#pragma unroll
    for (int i = 0; i < 8; ++i) {           // stage B: 128x64 bf16
      int idx = t + i * 256;
      int n = idx >> 4, c4 = idx & 15;
      *(ushort4*)(&Bs[n][c4 * 4]) = *(const ushort4*)(W1t + n * NF + k0 + c4 * 4);
    }
    __syncthreads();
#pragma unroll
    for (int ks = 0; ks < 64; ks += 32) {
      bf16x8 a[4], b[4];
#pragma unroll
      for (int mt = 0; mt < 4; ++mt) a[mt] = *(const bf16x8*)(&As[wm + mt * 16 + lrow][ks + quad * 8]);
#pragma unroll
      for (int nt = 0; nt < 4; ++nt) b[nt] = *(const bf16x8*)(&Bs[wn + nt * 16 + lrow][ks + quad * 8]);
#pragma unroll
      for (int mt = 0; mt < 4; ++mt)
#pragma unroll
        for (int nt = 0; nt < 4; ++nt)
          acc[mt][nt] = __builtin_amdgcn_mfma_f32_16x16x32_bf16(a[mt], b[nt], acc[mt][nt], 0, 0, 0);
    }
    __syncthreads();
  }
#pragma unroll
  for (int mt = 0; mt < 4; ++mt)
#pragma unroll
    for (int nt = 0; nt < 4; ++nt)
#pragma unroll
      for (int r = 0; r < 4; ++r) {
        int row = rowBase + wm + mt * 16 + quad * 4 + r;
        if (row < NN) {
          int col = wn + nt * 16 + lrow;
          h[(size_t)row * NH + col] = f2bf(acc[mt][nt][r]);
        }
      }
}

// ---------------- GEMM2: h3[NN][NC] bf16 = h2[NN][NH] bf16 @ W2 ----------------
__global__ __launch_bounds__(256) void k_gemm2(const unsigned short* __restrict__ h2,
                                               const unsigned short* __restrict__ W2t,
                                               unsigned short* __restrict__ h3) {
  __shared__ __align__(16) unsigned short As[256][72];
  __shared__ __align__(16) unsigned short Bs[64][72];
  int t = threadIdx.x;
  int rowBase = blockIdx.x * 256;
  int wave = t >> 6, lane = t & 63;
  int wm = wave * 64;
  int lrow = lane & 15, quad = lane >> 4;

  f32x4 acc[4][4];
#pragma unroll
  for (int i = 0; i < 4; ++i)
#pragma unroll
    for (int j = 0; j < 4; ++j) acc[i][j] = (f32x4){0.f, 0.f, 0.f, 0.f};

  for (int k0 = 0; k0 < NH; k0 += 64) {
#pragma unroll
    for (int i = 0; i < 16; ++i) {          // stage A: 256x64 bf16
      int idx = t + i * 256;
      int r = idx >> 4, c4 = idx & 15;
      int row = rowBase + r; if (row >= NN) row = NN - 1;
      *(ushort4*)(&As[r][c4 * 4]) = *(const ushort4*)(h2 + (size_t)row * NH + k0 + c4 * 4);
    }
#pragma unroll
    for (int i = 0; i < 4; ++i) {           // stage B: 64x64 bf16
      int idx = t + i * 256;
      int n = idx >> 4, c4 = idx & 15;
      *(ushort4*)(&Bs[n][c4 * 4]) = *(const ushort4*)(W2t + n * NH + k0 + c4 * 4);
    }
    __syncthreads();
#pragma unroll
    for (int ks = 0; ks < 64; ks += 32) {
      bf16x8 a[4], b[4];
#pragma unroll
      for (int mt = 0; mt < 4; ++mt) a[mt] = *(const bf16x8*)(&As[wm + mt * 16 + lrow][ks + quad * 8]);
#pragma unroll
      for (int nt = 0; nt < 4; ++nt) b[nt] = *(const bf16x8*)(&Bs[nt * 16 + lrow][ks + quad * 8]);
#pragma unroll
      for (int mt = 0; mt < 4; ++mt)
#pragma unroll
        for (int nt = 0; nt < 4; ++nt)
          acc[mt][nt] = __builtin_amdgcn_mfma_f32_16x16x32_bf16(a[mt], b[nt], acc[mt][nt], 0, 0, 0);
    }
    __syncthreads();
  }
#pragma unroll
  for (int mt = 0; mt < 4; ++mt)
#pragma unroll
    for (int nt = 0; nt < 4; ++nt)
#pragma unroll
      for (int r = 0; r < 4; ++r) {
        int row = rowBase + wm + mt * 16 + quad * 4 + r;
        if (row < NN) {
          int col = nt * 16 + lrow;
          h3[(size_t)row * NC + col] = f2bf(acc[mt][nt][r]);
        }
      }
}

// ---------------- propagate 1: h2 = relu(seg_sum(w * h[src]) + b1), D=128 ----------------
// half-wave per edge: lanes 0-31 edge j, lanes 32-63 edge j+1; uint2 (4 cols) per lane.
__global__ __launch_bounds__(256) void k_prop1(const int* __restrict__ rowptr,
                                               const int2* __restrict__ sedge,
                                               const unsigned short* __restrict__ h,
                                               const float4* __restrict__ b1v,
                                               unsigned short* __restrict__ h2) {
  __shared__ int2 se[4][64];
  int w = threadIdx.x >> 6, lane = threadIdx.x & 63;
  int half = lane >> 5, l2 = lane & 31;
  int node = blockIdx.x * 4 + w;
  int e0 = rowptr[node], e1 = rowptr[node + 1];
  float a0 = 0.f, a1 = 0.f, a2 = 0.f, a3 = 0.f;
  for (int e = e0; e < e1; e += 64) {
    int cnt = e1 - e; if (cnt > 64) cnt = 64;
    if (lane < cnt) se[w][lane] = sedge[e + lane];
    asm volatile("s_waitcnt lgkmcnt(0)" ::: "memory");
    for (int j = 0; j < cnt; j += 2) {
      int idx = j + half;
      int2 ed = (idx < cnt) ? se[w][idx] : make_int2(0, 0);
      float wj = __int_as_float(ed.y);
      uint2 hv = *(const uint2*)(h + (size_t)ed.x * NH + l2 * 4);
      a0 += wj * bf2f((unsigned short)(hv.x & 0xffffu));
      a1 += wj * bf2f((unsigned short)(hv.x >> 16));
      a2 += wj * bf2f((unsigned short)(hv.y & 0xffffu));
      a3 += wj * bf2f((unsigned short)(hv.y >> 16));
    }
  }
  a0 += __shfl_xor(a0, 32); a1 += __shfl_xor(a1, 32);
  a2 += __shfl_xor(a2, 32); a3 += __shfl_xor(a3, 32);
  if (half == 0) {
    float4 b = b1v[l2];
    float o0 = fmaxf(a0 + b.x, 0.f), o1 = fmaxf(a1 + b.y, 0.f);
    float o2 = fmaxf(a2 + b.z, 0.f), o3 = fmaxf(a3 + b.w, 0.f);
    uint2 p;
    p.x = ((unsigned int)f2bf(o1) << 16) | (unsigned int)f2bf(o0);
    p.y = ((unsigned int)f2bf(o3) << 16) | (unsigned int)f2bf(o2);
    *(uint2*)(h2 + (size_t)node * NH + l2 * 4) = p;
  }
}

// ---------------- propagate 2: out = seg_sum(w * h3[src]) + b2, D=64 ----------------
// quarter-wave per edge: 4 edges per iteration; uint2 (4 cols) per lane.
__global__ __launch_bounds__(256) void k_prop2(const int* __restrict__ rowptr,
                                               const int2* __restrict__ sedge,
                                               const unsigned short* __restrict__ h3,
                                               const float4* __restrict__ b2v,
                                               float* __restrict__ out) {
  __shared__ int2 se[4][64];
  int w = threadIdx.x >> 6, lane = threadIdx.x & 63;
  int q = lane >> 4, l4 = lane & 15;
  int node = blockIdx.x * 4 + w;
  int e0 = rowptr[node], e1 = rowptr[node + 1];
  float a0 = 0.f, a1 = 0.f, a2 = 0.f, a3 = 0.f;
  for (int e = e0; e < e1; e += 64) {
    int cnt = e1 - e; if (cnt > 64) cnt = 64;
    if (lane < cnt) se[w][lane] = sedge[e + lane];
    asm volatile("s_waitcnt lgkmcnt(0)" ::: "memory");
    for (int j = 0; j < cnt; j += 4) {
      int idx = j + q;
      int2 ed = (idx < cnt) ? se[w][idx] : make_int2(0, 0);
      float wj = __int_as_float(ed.y);
      uint2 hv = *(const uint2*)(h3 + (size_t)ed.x * NC + l4 * 4);
      a0 += wj * bf2f((unsigned short)(hv.x & 0xffffu));
      a1 += wj * bf2f((unsigned short)(hv.x >> 16));
      a2 += wj * bf2f((unsigned short)(hv.y & 0xffffu));
      a3 += wj * bf2f((unsigned short)(hv.y >> 16));
    }
  }
  a0 += __shfl_xor(a0, 16); a1 += __shfl_xor(a1, 16);
  a2 += __shfl_xor(a2, 16); a3 += __shfl_xor(a3, 16);
  a0 += __shfl_xor(a0, 32); a1 += __shfl_xor(a1, 32);
  a2 += __shfl_xor(a2, 32); a3 += __shfl_xor(a3, 32);
  if (q == 0) {
    float4 b = b2v[l4];
    float4 o = make_float4(a0 + b.x, a1 + b.y, a2 + b.z, a3 + b.w);
    *(float4*)(out + (size_t)node * NC + l4 * 4) = o;
  }
}

extern "C" void kernel_launch(void* const* d_in, const int* in_sizes, int n_in,
                              void* d_out, int out_size, void* d_ws, size_t ws_size,
                              hipStream_t stream) {
  const float* x = (const float*)d_in[0];
  const int* ei = (const int*)d_in[1];   // int32 on device (harness convention)
  const float* ew = (const float*)d_in[2];
  const float* W1 = (const float*)d_in[3];
  const float* b1 = (const float*)d_in[4];
  const float* W2 = (const float*)d_in[5];
  const float* b2 = (const float*)d_in[6];
  float* out = (float*)d_out;

  char* ws = (char*)d_ws;
  size_t off = 0;
  auto alloc = [&](size_t bytes) {
    char* p = ws + off;
    off = (off + bytes + 255) & ~(size_t)255;
    return p;
  };
  unsigned short* W1t = (unsigned short*)alloc((size_t)NF * NH * 2);
  unsigned short* W2t = (unsigned short*)alloc((size_t)NH * NC * 2);
  unsigned short* h   = (unsigned short*)alloc((size_t)NN * NH * 2);
  unsigned short* h2  = (unsigned short*)alloc((size_t)NN * NH * 2);
  unsigned short* h3  = h;  // h dead after prop1; alias to save ws
  int* rowptr   = (int*)alloc((size_t)(NN + 1) * 4);
  int* offs     = (int*)alloc((size_t)NN * 4);
  int* counts   = (int*)alloc((size_t)NN * 4);
  int* partials = (int*)alloc(4096);
  int2* sedge   = (int2*)alloc((size_t)NE * 8);

  const int NB = (NN + 1023) / 1024;  // 98

  k_init<<<(NN + 255) / 256, 256, 0, stream>>>(W1, W2, W1t, W2t, counts);
  k_count<<<(NE + 255) / 256, 256, 0, stream>>>(ei, counts);
  k_gemm1<<<(NN + 127) / 128, 256, 0, stream>>>(x, W1t, h);
  k_scan1<<<NB, 256, 0, stream>>>(counts, partials);
  k_scan2<<<1, 128, 0, stream>>>(partials, NB);
  k_scan3<<<NB, 256, 0, stream>>>(counts, partials, rowptr, offs);
  k_scatter<<<(NE + 255) / 256, 256, 0, stream>>>(ei, ew, offs, sedge);
  k_prop1<<<NN / 4, 256, 0, stream>>>(rowptr, sedge, h, (const float4*)b1, h2);
  k_gemm2<<<(NN + 255) / 256, 256, 0, stream>>>(h2, W2t, h3);
  k_prop2<<<NN / 4, 256, 0, stream>>>(rowptr, sedge, h3, (const float4*)b2, out);
}

// Round 4
// 525.989 us; speedup vs baseline: 1.3613x; 1.2112x over previous
//
#include <hip/hip_runtime.h>

#define NN 100000
#define NE 1600000
#define NF 512
#define NH 128
#define NC 64
#define NPART 391            // ceil(NN/256): partition = dst>>8

typedef __attribute__((ext_vector_type(8))) short bf16x8;
typedef __attribute__((ext_vector_type(4))) float f32x4;

static __device__ __forceinline__ unsigned short f2bf(float f) {
  unsigned int u = __float_as_uint(f);
  u += 0x7fffu + ((u >> 16) & 1u);   // RNE
  return (unsigned short)(u >> 16);
}
static __device__ __forceinline__ float bf2f(unsigned short s) {
  return __uint_as_float(((unsigned int)s) << 16);
}

// ---------------- init: zero part totals + convert/transpose weights ----------------
__global__ void k_init(const float* __restrict__ W1, const float* __restrict__ W2,
                       unsigned short* __restrict__ W1t, unsigned short* __restrict__ W2t,
                       int* __restrict__ partTotals) {
  int i = blockIdx.x * 256 + threadIdx.x;
  if (i < NPART + 1) partTotals[i] = 0;
  if (i < NF * NH) {
    int k = i / NH, n = i % NH;
    W1t[n * NF + k] = f2bf(W1[i]);
  }
  int j = i - NF * NH;
  if (j >= 0 && j < NH * NC) {
    int k = j / NC, n = j % NC;
    W2t[n * NH + k] = f2bf(W2[j]);
  }
}

// ---------------- pass A1: partition histogram (LDS-aggregated) ----------------
__global__ __launch_bounds__(256) void k_hist(const int* __restrict__ ei,
                                              int* __restrict__ partTotals) {
  __shared__ int hist[NPART];
  int t = threadIdx.x;
  for (int i = t; i < NPART; i += 256) hist[i] = 0;
  __syncthreads();
  int base = blockIdx.x * 2048;
#pragma unroll
  for (int j = 0; j < 8; ++j) {
    int e = base + j * 256 + t;
    if (e < NE) atomicAdd(&hist[ei[NE + e] >> 8], 1);
  }
  __syncthreads();
  for (int i = t; i < NPART; i += 256)
    if (hist[i]) atomicAdd(&partTotals[i], hist[i]);
}

// ---------------- scan partition totals -> starts & cursors ----------------
__global__ __launch_bounds__(512) void k_pscan(const int* __restrict__ partTotals,
                                               int* __restrict__ partStart,
                                               int* __restrict__ partCursor,
                                               int* __restrict__ rowptr) {
  __shared__ int sd[512];
  int t = threadIdx.x;
  int v = (t < NPART) ? partTotals[t] : 0;
  sd[t] = v; __syncthreads();
  for (int o = 1; o < 512; o <<= 1) {
    int y = (t >= o) ? sd[t - o] : 0;
    __syncthreads();
    sd[t] += y;
    __syncthreads();
  }
  int excl = sd[t] - v;
  if (t < NPART) { partStart[t] = excl; partCursor[t] = excl; }
  if (t == NPART - 1) partStart[NPART] = sd[t];  // == NE
  if (t == 0) rowptr[NN] = NE;
}

// ---------------- pass A2: partition the edges (run-coalesced writes) ----------------
__global__ __launch_bounds__(256) void k_part(const int* __restrict__ ei,
                                              const float* __restrict__ ew,
                                              int* __restrict__ partCursor,
                                              int4* __restrict__ tmp) {
  __shared__ int hist[NPART];
  __shared__ int cur[NPART];
  int t = threadIdx.x;
  for (int i = t; i < NPART; i += 256) hist[i] = 0;
  __syncthreads();
  int base = blockIdx.x * 2048;
  int d[8], s[8], wb[8];
#pragma unroll
  for (int j = 0; j < 8; ++j) {
    int e = base + j * 256 + t;
    if (e < NE) {
      d[j] = ei[NE + e]; s[j] = ei[e]; wb[j] = __float_as_int(ew[e]);
      atomicAdd(&hist[d[j] >> 8], 1);
    } else d[j] = -1;
  }
  __syncthreads();
  for (int i = t; i < NPART; i += 256) {
    int c = hist[i];
    cur[i] = c ? atomicAdd(&partCursor[i], c) : 0;
  }
  __syncthreads();
#pragma unroll
  for (int j = 0; j < 8; ++j) {
    if (d[j] >= 0) {
      int pos = atomicAdd(&cur[d[j] >> 8], 1);
      tmp[pos] = make_int4(s[j], wb[j], d[j], 0);
    }
  }
}

// ---------------- pass B: per-partition counting sort by node ----------------
// emits rowptr (per-node) + fully-sorted sedge with coalesced writes.
__global__ __launch_bounds__(256) void k_sortp(const int* __restrict__ partStart,
                                               const int4* __restrict__ tmp,
                                               int2* __restrict__ sedge,
                                               int* __restrict__ rowptr) {
  __shared__ int cnt[256];
  __shared__ int sc[256];
  __shared__ int wcur[256];
  __shared__ int2 sorted[5120];   // 40 KB; partition size ~4096 +- 64 (16 sigma margin)
  int p = blockIdx.x, t = threadIdx.x;
  int r0 = partStart[p], r1 = partStart[p + 1];
  int n = r1 - r0;
  cnt[t] = 0; __syncthreads();
  for (int i = t; i < n; i += 256) {
    int4 v = tmp[r0 + i];
    atomicAdd(&cnt[v.z & 255], 1);
  }
  __syncthreads();
  int c = cnt[t];
  sc[t] = c; __syncthreads();
  for (int o = 1; o < 256; o <<= 1) {
    int y = (t >= o) ? sc[t - o] : 0;
    __syncthreads();
    sc[t] += y;
    __syncthreads();
  }
  int excl = sc[t] - c;
  int node = p * 256 + t;
  if (node < NN) rowptr[node] = r0 + excl;
  wcur[t] = excl;
  __syncthreads();
  for (int i = t; i < n; i += 256) {
    int4 v = tmp[r0 + i];                       // L2-hot re-read
    int lpos = atomicAdd(&wcur[v.z & 255], 1);
    sorted[lpos] = make_int2(v.x, v.y);
  }
  __syncthreads();
  for (int i = t; i < n; i += 256) sedge[r0 + i] = sorted[i];
}

// ---------------- GEMM1: h[NN][NH] bf16 = x[NN][NF] f32 @ W1 ----------------
__global__ __launch_bounds__(256) void k_gemm1(const float* __restrict__ x,
                                               const unsigned short* __restrict__ W1t,
                                               unsigned short* __restrict__ h) {
  __shared__ __align__(16) unsigned short As[128][72];  // [m][k], +8 pad
  __shared__ __align__(16) unsigned short Bs[128][72];  // [n][k], +8 pad
  int t = threadIdx.x;
  int rowBase = blockIdx.x * 128;
  int wave = t >> 6, lane = t & 63;
  int wm = (wave & 1) * 64, wn = (wave >> 1) * 64;
  int lrow = lane & 15, quad = lane >> 4;

  f32x4 acc[4][4];
#pragma unroll
  for (int i = 0; i < 4; ++i)
#pragma unroll
    for (int j = 0; j < 4; ++j) acc[i][j] = (f32x4){0.f, 0.f, 0.f, 0.f};

  for (int k0 = 0; k0 < NF; k0 += 64) {
#pragma unroll
    for (int i = 0; i < 8; ++i) {           // stage A: 128x64 f32 -> bf16
      int idx = t + i * 256;
      int r = idx >> 4, c4 = idx & 15;
      int row = rowBase + r; if (row >= NN) row = NN - 1;
      const float4 v = *(const float4*)(x + (size_t)row * NF + k0 + c4 * 4);
      ushort4 sv;
      sv.x = f2bf(v.x); sv.y = f2bf(v.y); sv.z = f2bf(v.z); sv.w = f2bf(v.w);
      *(ushort4*)(&As[r][c4 * 4]) = sv;
    }
#pragma unroll
    for (int i = 0; i < 8; ++i) {           // stage B: 128x64 bf16
      int idx = t + i * 256;
      int n = idx >> 4, c4 = idx & 15;
      *(ushort4*)(&Bs[n][c4 * 4]) = *(const ushort4*)(W1t + n * NF + k0 + c4 * 4);
    }
    __syncthreads();
#pragma unroll
    for (int ks = 0; ks < 64; ks += 32) {
      bf16x8 a[4], b[4];
#pragma unroll
      for (int mt = 0; mt < 4; ++mt) a[mt] = *(const bf16x8*)(&As[wm + mt * 16 + lrow][ks + quad * 8]);
#pragma unroll
      for (int nt = 0; nt < 4; ++nt) b[nt] = *(const bf16x8*)(&Bs[wn + nt * 16 + lrow][ks + quad * 8]);
#pragma unroll
      for (int mt = 0; mt < 4; ++mt)
#pragma unroll
        for (int nt = 0; nt < 4; ++nt)
          acc[mt][nt] = __builtin_amdgcn_mfma_f32_16x16x32_bf16(a[mt], b[nt], acc[mt][nt], 0, 0, 0);
    }
    __syncthreads();
  }
#pragma unroll
  for (int mt = 0; mt < 4; ++mt)
#pragma unroll
    for (int nt = 0; nt < 4; ++nt)
#pragma unroll
      for (int r = 0; r < 4; ++r) {
        int row = rowBase + wm + mt * 16 + quad * 4 + r;
        if (row < NN) {
          int col = wn + nt * 16 + lrow;
          h[(size_t)row * NH + col] = f2bf(acc[mt][nt][r]);
        }
      }
}

// ---------------- GEMM2: h3[NN][NC] bf16 = h2[NN][NH] bf16 @ W2 ----------------
__global__ __launch_bounds__(256) void k_gemm2(const unsigned short* __restrict__ h2,
                                               const unsigned short* __restrict__ W2t,
                                               unsigned short* __restrict__ h3) {
  __shared__ __align__(16) unsigned short As[256][72];
  __shared__ __align__(16) unsigned short Bs[64][72];
  int t = threadIdx.x;
  int rowBase = blockIdx.x * 256;
  int wave = t >> 6, lane = t & 63;
  int wm = wave * 64;
  int lrow = lane & 15, quad = lane >> 4;

  f32x4 acc[4][4];
#pragma unroll
  for (int i = 0; i < 4; ++i)
#pragma unroll
    for (int j = 0; j < 4; ++j) acc[i][j] = (f32x4){0.f, 0.f, 0.f, 0.f};

  for (int k0 = 0; k0 < NH; k0 += 64) {
#pragma unroll
    for (int i = 0; i < 16; ++i) {          // stage A: 256x64 bf16
      int idx = t + i * 256;
      int r = idx >> 4, c4 = idx & 15;
      int row = rowBase + r; if (row >= NN) row = NN - 1;
      *(ushort4*)(&As[r][c4 * 4]) = *(const ushort4*)(h2 + (size_t)row * NH + k0 + c4 * 4);
    }
#pragma unroll
    for (int i = 0; i < 4; ++i) {           // stage B: 64x64 bf16
      int idx = t + i * 256;
      int n = idx >> 4, c4 = idx & 15;
      *(ushort4*)(&Bs[n][c4 * 4]) = *(const ushort4*)(W2t + n * NH + k0 + c4 * 4);
    }
    __syncthreads();
#pragma unroll
    for (int ks = 0; ks < 64; ks += 32) {
      bf16x8 a[4], b[4];
#pragma unroll
      for (int mt = 0; mt < 4; ++mt) a[mt] = *(const bf16x8*)(&As[wm + mt * 16 + lrow][ks + quad * 8]);
#pragma unroll
      for (int nt = 0; nt < 4; ++nt) b[nt] = *(const bf16x8*)(&Bs[nt * 16 + lrow][ks + quad * 8]);
#pragma unroll
      for (int mt = 0; mt < 4; ++mt)
#pragma unroll
        for (int nt = 0; nt < 4; ++nt)
          acc[mt][nt] = __builtin_amdgcn_mfma_f32_16x16x32_bf16(a[mt], b[nt], acc[mt][nt], 0, 0, 0);
    }
    __syncthreads();
  }
#pragma unroll
  for (int mt = 0; mt < 4; ++mt)
#pragma unroll
    for (int nt = 0; nt < 4; ++nt)
#pragma unroll
      for (int r = 0; r < 4; ++r) {
        int row = rowBase + wm + mt * 16 + quad * 4 + r;
        if (row < NN) {
          int col = nt * 16 + lrow;
          h3[(size_t)row * NC + col] = f2bf(acc[mt][nt][r]);
        }
      }
}

// ---------------- propagate 1: h2 = relu(seg_sum(w * h[src]) + b1), D=128 ----------------
__global__ __launch_bounds__(256) void k_prop1(const int* __restrict__ rowptr,
                                               const int2* __restrict__ sedge,
                                               const unsigned short* __restrict__ h,
                                               const float4* __restrict__ b1v,
                                               unsigned short* __restrict__ h2) {
  __shared__ int2 se[4][64];
  int w = threadIdx.x >> 6, lane = threadIdx.x & 63;
  int half = lane >> 5, l2 = lane & 31;
  int node = blockIdx.x * 4 + w;
  int e0 = rowptr[node], e1 = rowptr[node + 1];
  float a0 = 0.f, a1 = 0.f, a2 = 0.f, a3 = 0.f;
  for (int e = e0; e < e1; e += 64) {
    int cnt = e1 - e; if (cnt > 64) cnt = 64;
    if (lane < cnt) se[w][lane] = sedge[e + lane];
    asm volatile("s_waitcnt lgkmcnt(0)" ::: "memory");
    for (int j = 0; j < cnt; j += 2) {
      int idx = j + half;
      int2 ed = (idx < cnt) ? se[w][idx] : make_int2(0, 0);
      float wj = __int_as_float(ed.y);
      uint2 hv = *(const uint2*)(h + (size_t)ed.x * NH + l2 * 4);
      a0 += wj * bf2f((unsigned short)(hv.x & 0xffffu));
      a1 += wj * bf2f((unsigned short)(hv.x >> 16));
      a2 += wj * bf2f((unsigned short)(hv.y & 0xffffu));
      a3 += wj * bf2f((unsigned short)(hv.y >> 16));
    }
  }
  a0 += __shfl_xor(a0, 32); a1 += __shfl_xor(a1, 32);
  a2 += __shfl_xor(a2, 32); a3 += __shfl_xor(a3, 32);
  if (half == 0) {
    float4 b = b1v[l2];
    float o0 = fmaxf(a0 + b.x, 0.f), o1 = fmaxf(a1 + b.y, 0.f);
    float o2 = fmaxf(a2 + b.z, 0.f), o3 = fmaxf(a3 + b.w, 0.f);
    uint2 p;
    p.x = ((unsigned int)f2bf(o1) << 16) | (unsigned int)f2bf(o0);
    p.y = ((unsigned int)f2bf(o3) << 16) | (unsigned int)f2bf(o2);
    *(uint2*)(h2 + (size_t)node * NH + l2 * 4) = p;
  }
}

// ---------------- propagate 2: out = seg_sum(w * h3[src]) + b2, D=64 ----------------
__global__ __launch_bounds__(256) void k_prop2(const int* __restrict__ rowptr,
                                               const int2* __restrict__ sedge,
                                               const unsigned short* __restrict__ h3,
                                               const float4* __restrict__ b2v,
                                               float* __restrict__ out) {
  __shared__ int2 se[4][64];
  int w = threadIdx.x >> 6, lane = threadIdx.x & 63;
  int q = lane >> 4, l4 = lane & 15;
  int node = blockIdx.x * 4 + w;
  int e0 = rowptr[node], e1 = rowptr[node + 1];
  float a0 = 0.f, a1 = 0.f, a2 = 0.f, a3 = 0.f;
  for (int e = e0; e < e1; e += 64) {
    int cnt = e1 - e; if (cnt > 64) cnt = 64;
    if (lane < cnt) se[w][lane] = sedge[e + lane];
    asm volatile("s_waitcnt lgkmcnt(0)" ::: "memory");
    for (int j = 0; j < cnt; j += 4) {
      int idx = j + q;
      int2 ed = (idx < cnt) ? se[w][idx] : make_int2(0, 0);
      float wj = __int_as_float(ed.y);
      uint2 hv = *(const uint2*)(h3 + (size_t)ed.x * NC + l4 * 4);
      a0 += wj * bf2f((unsigned short)(hv.x & 0xffffu));
      a1 += wj * bf2f((unsigned short)(hv.x >> 16));
      a2 += wj * bf2f((unsigned short)(hv.y & 0xffffu));
      a3 += wj * bf2f((unsigned short)(hv.y >> 16));
    }
  }
  a0 += __shfl_xor(a0, 16); a1 += __shfl_xor(a1, 16);
  a2 += __shfl_xor(a2, 16); a3 += __shfl_xor(a3, 16);
  a0 += __shfl_xor(a0, 32); a1 += __shfl_xor(a1, 32);
  a2 += __shfl_xor(a2, 32); a3 += __shfl_xor(a3, 32);
  if (q == 0) {
    float4 b = b2v[l4];
    float4 o = make_float4(a0 + b.x, a1 + b.y, a2 + b.z, a3 + b.w);
    *(float4*)(out + (size_t)node * NC + l4 * 4) = o;
  }
}

extern "C" void kernel_launch(void* const* d_in, const int* in_sizes, int n_in,
                              void* d_out, int out_size, void* d_ws, size_t ws_size,
                              hipStream_t stream) {
  const float* x = (const float*)d_in[0];
  const int* ei = (const int*)d_in[1];   // int32 on device (harness convention)
  const float* ew = (const float*)d_in[2];
  const float* W1 = (const float*)d_in[3];
  const float* b1 = (const float*)d_in[4];
  const float* W2 = (const float*)d_in[5];
  const float* b2 = (const float*)d_in[6];
  float* out = (float*)d_out;

  char* ws = (char*)d_ws;
  size_t off = 0;
  auto alloc = [&](size_t bytes) {
    char* p = ws + off;
    off = (off + bytes + 255) & ~(size_t)255;
    return p;
  };
  unsigned short* W1t = (unsigned short*)alloc((size_t)NF * NH * 2);
  unsigned short* W2t = (unsigned short*)alloc((size_t)NH * NC * 2);
  unsigned short* h   = (unsigned short*)alloc((size_t)NN * NH * 2);
  unsigned short* h2  = (unsigned short*)alloc((size_t)NN * NH * 2);
  unsigned short* h3  = h;  // h dead after prop1; alias to save ws
  int* rowptr     = (int*)alloc((size_t)(NN + 1) * 4);
  int* partTotals = (int*)alloc((NPART + 1) * 4);
  int* partStart  = (int*)alloc((NPART + 1) * 4);
  int* partCursor = (int*)alloc((NPART + 1) * 4);
  int2* sedge     = (int2*)alloc((size_t)NE * 8);
  int4* tmp       = (int4*)alloc((size_t)NE * 16);

  const int NBE = (NE + 2047) / 2048;  // 782

  k_init<<<(NN + 255) / 256, 256, 0, stream>>>(W1, W2, W1t, W2t, partTotals);
  k_hist<<<NBE, 256, 0, stream>>>(ei, partTotals);
  k_gemm1<<<(NN + 127) / 128, 256, 0, stream>>>(x, W1t, h);
  k_pscan<<<1, 512, 0, stream>>>(partTotals, partStart, partCursor, rowptr);
  k_part<<<NBE, 256, 0, stream>>>(ei, ew, partCursor, tmp);
  k_sortp<<<NPART, 256, 0, stream>>>(partStart, tmp, sedge, rowptr);
  k_prop1<<<NN / 4, 256, 0, stream>>>(rowptr, sedge, h, (const float4*)b1, h2);
  k_gemm2<<<(NN + 255) / 256, 256, 0, stream>>>(h2, W2t, h3);
  k_prop2<<<NN / 4, 256, 0, stream>>>(rowptr, sedge, h3, (const float4*)b2, out);
}

// Round 5
// 505.870 us; speedup vs baseline: 1.4154x; 1.0398x over previous
//
#include <hip/hip_runtime.h>

#define NN 100000
#define NE 1600000
#define NF 512
#define NH 128
#define NC 64
#define NPART 782            // ceil(NN/128): partition = dst>>7 (128 nodes each)
#define NBH 782              // hist blocks, 2048 edges each
#define NBP 196              // part blocks, 8192 edges each
#define CONVB 288            // weight-conversion blocks
#define SORTBUF 2816         // partition size ~2048 +- 45 (17 sigma margin)

typedef __attribute__((ext_vector_type(8))) short bf16x8;
typedef __attribute__((ext_vector_type(4))) float f32x4;

static __device__ __forceinline__ unsigned short f2bf(float f) {
  unsigned int u = __float_as_uint(f);
  u += 0x7fffu + ((u >> 16) & 1u);   // RNE
  return (unsigned short)(u >> 16);
}
static __device__ __forceinline__ float bf2f(unsigned short s) {
  return __uint_as_float(((unsigned int)s) << 16);
}

// ---------------- zero partition totals ----------------
__global__ void k_zero0(int* __restrict__ p) {
  int i = blockIdx.x * 256 + threadIdx.x;
  if (i < NPART + 1) p[i] = 0;
}

// ---------------- K1: partition histogram (blocks 0..781) + weight conv (782..1069) ----------------
__global__ __launch_bounds__(256) void k_hist_conv(const int* __restrict__ ei,
                                                   int* __restrict__ partTotals,
                                                   const float* __restrict__ W1,
                                                   const float* __restrict__ W2,
                                                   unsigned short* __restrict__ W1t,
                                                   unsigned short* __restrict__ W2t) {
  int t = threadIdx.x;
  if (blockIdx.x < NBH) {
    __shared__ int hist[NPART];
    for (int i = t; i < NPART; i += 256) hist[i] = 0;
    __syncthreads();
    int base = blockIdx.x * 2048;
#pragma unroll
    for (int j = 0; j < 8; ++j) {
      int e = base + j * 256 + t;
      if (e < NE) atomicAdd(&hist[ei[NE + e] >> 7], 1);
    }
    __syncthreads();
    for (int i = t; i < NPART; i += 256)
      if (hist[i]) atomicAdd(&partTotals[i], hist[i]);
  } else {
    int i = (blockIdx.x - NBH) * 256 + t;
    if (i < NF * NH) {
      int k = i / NH, n = i % NH;
      W1t[n * NF + k] = f2bf(W1[i]);
    }
    int j = i - NF * NH;
    if (j >= 0 && j < NH * NC) {
      int k = j / NC, n = j % NC;
      W2t[n * NH + k] = f2bf(W2[j]);
    }
  }
}

// ---------------- scan partition totals -> starts & cursors ----------------
__global__ __launch_bounds__(1024) void k_pscan(const int* __restrict__ partTotals,
                                                int* __restrict__ partStart,
                                                int* __restrict__ partCursor,
                                                int* __restrict__ rowptr) {
  __shared__ int sd[1024];
  int t = threadIdx.x;
  int v = (t < NPART) ? partTotals[t] : 0;
  sd[t] = v; __syncthreads();
  for (int o = 1; o < 1024; o <<= 1) {
    int y = (t >= o) ? sd[t - o] : 0;
    __syncthreads();
    sd[t] += y;
    __syncthreads();
  }
  int excl = sd[t] - v;
  if (t < NPART) { partStart[t] = excl; partCursor[t] = excl; }
  if (t == NPART - 1) partStart[NPART] = sd[t];  // == NE
  if (t == 0) rowptr[NN] = NE;
}

// ---------------- K3: edge partition pass (blocks 0..195) + GEMM1 (blocks 196..977) ----------------
// gemm1: h[NN][NH] bf16 = x[NN][NF] f32 @ W1 (128x128 tile, 16x16x32 MFMA)
__global__ __launch_bounds__(256) void k_part_gemm1(const int* __restrict__ ei,
                                                    const float* __restrict__ ew,
                                                    int* __restrict__ partCursor,
                                                    int2* __restrict__ tmp,
                                                    const float* __restrict__ x,
                                                    const unsigned short* __restrict__ W1t,
                                                    unsigned short* __restrict__ h) {
  __shared__ __align__(16) char smem[36864];
  int t = threadIdx.x;
  if (blockIdx.x < NBP) {
    // ---- edge partitioning: 8192 edges, two global passes, run-coalesced writes ----
    int* hist = (int*)smem;           // NPART ints
    int* cur = hist + NPART;          // NPART ints
    for (int i = t; i < NPART; i += 256) hist[i] = 0;
    __syncthreads();
    int base = blockIdx.x * 8192;
#pragma unroll
    for (int j = 0; j < 32; ++j) {
      int e = base + j * 256 + t;
      if (e < NE) atomicAdd(&hist[ei[NE + e] >> 7], 1);
    }
    __syncthreads();
    for (int i = t; i < NPART; i += 256) {
      int c = hist[i];
      cur[i] = c ? atomicAdd(&partCursor[i], c) : 0;
    }
    __syncthreads();
#pragma unroll
    for (int j = 0; j < 32; ++j) {
      int e = base + j * 256 + t;
      if (e < NE) {
        int d = ei[NE + e];
        int pos = atomicAdd(&cur[d >> 7], 1);
        // pack: src (bits 0..16) | dst_local (bits 20..26); w bits in .y
        tmp[pos] = make_int2(ei[e] | ((d & 127) << 20), __float_as_int(ew[e]));
      }
    }
  } else {
    // ---- GEMM1 tile ----
    typedef unsigned short row72[72];
    row72* As = (row72*)smem;                       // 128 x 72 shorts
    row72* Bs = (row72*)(smem + 128 * 72 * 2);      // 128 x 72 shorts
    int rowBase = (blockIdx.x - NBP) * 128;
    int wave = t >> 6, lane = t & 63;
    int wm = (wave & 1) * 64, wn = (wave >> 1) * 64;
    int lrow = lane & 15, quad = lane >> 4;

    f32x4 acc[4][4];
#pragma unroll
    for (int i = 0; i < 4; ++i)
#pragma unroll
      for (int j = 0; j < 4; ++j) acc[i][j] = (f32x4){0.f, 0.f, 0.f, 0.f};

    for (int k0 = 0; k0 < NF; k0 += 64) {
#pragma unroll
      for (int i = 0; i < 8; ++i) {           // stage A: 128x64 f32 -> bf16
        int idx = t + i * 256;
        int r = idx >> 4, c4 = idx & 15;
        int row = rowBase + r; if (row >= NN) row = NN - 1;
        const float4 v = *(const float4*)(x + (size_t)row * NF + k0 + c4 * 4);
        ushort4 sv;
        sv.x = f2bf(v.x); sv.y = f2bf(v.y); sv.z = f2bf(v.z); sv.w = f2bf(v.w);
        *(ushort4*)(&As[r][c4 * 4]) = sv;
      }
#pragma unroll
      for (int i = 0; i < 8; ++i) {           // stage B: 128x64 bf16
        int idx = t + i * 256;
        int n = idx >> 4, c4 = idx & 15;
        *(ushort4*)(&Bs[n][c4 * 4]) = *(const ushort4*)(W1t + n * NF + k0 + c4 * 4);
      }
      __syncthreads();
#pragma unroll
      for (int ks = 0; ks < 64; ks += 32) {
        bf16x8 a[4], b[4];
#pragma unroll
        for (int mt = 0; mt < 4; ++mt) a[mt] = *(const bf16x8*)(&As[wm + mt * 16 + lrow][ks + quad * 8]);
#pragma unroll
        for (int nt = 0; nt < 4; ++nt) b[nt] = *(const bf16x8*)(&Bs[wn + nt * 16 + lrow][ks + quad * 8]);
#pragma unroll
        for (int mt = 0; mt < 4; ++mt)
#pragma unroll
          for (int nt = 0; nt < 4; ++nt)
            acc[mt][nt] = __builtin_amdgcn_mfma_f32_16x16x32_bf16(a[mt], b[nt], acc[mt][nt], 0, 0, 0);
      }
      __syncthreads();
    }
#pragma unroll
    for (int mt = 0; mt < 4; ++mt)
#pragma unroll
      for (int nt = 0; nt < 4; ++nt)
#pragma unroll
        for (int r = 0; r < 4; ++r) {
          int row = rowBase + wm + mt * 16 + quad * 4 + r;
          if (row < NN) {
            int col = wn + nt * 16 + lrow;
            h[(size_t)row * NH + col] = f2bf(acc[mt][nt][r]);
          }
        }
  }
}

// ---------------- pass B: per-partition counting sort by node (128 bins) ----------------
__global__ __launch_bounds__(256) void k_sortp(const int* __restrict__ partStart,
                                               const int2* __restrict__ tmp,
                                               int2* __restrict__ sedge,
                                               int* __restrict__ rowptr) {
  __shared__ int cnt[128];
  __shared__ int sc[128];
  __shared__ int wcur[128];
  __shared__ int2 sorted[SORTBUF];
  int p = blockIdx.x, t = threadIdx.x;
  int r0 = partStart[p], r1 = partStart[p + 1];
  int n = r1 - r0;
  if (t < 128) cnt[t] = 0;
  __syncthreads();
  for (int i = t; i < n; i += 256) {
    int2 v = tmp[r0 + i];
    atomicAdd(&cnt[v.x >> 20], 1);
  }
  __syncthreads();
  if (t < 128) sc[t] = cnt[t];
  __syncthreads();
  for (int o = 1; o < 128; o <<= 1) {
    int y = (t >= o && t < 128) ? sc[t - o] : 0;
    __syncthreads();
    if (t < 128) sc[t] += y;
    __syncthreads();
  }
  if (t < 128) {
    int excl = sc[t] - cnt[t];
    int node = p * 128 + t;
    if (node < NN) rowptr[node] = r0 + excl;
    wcur[t] = excl;
  }
  __syncthreads();
  for (int i = t; i < n; i += 256) {
    int2 v = tmp[r0 + i];                       // L2-hot re-read
    int lpos = atomicAdd(&wcur[v.x >> 20], 1);
    sorted[lpos] = make_int2(v.x & 0xFFFFF, v.y);
  }
  __syncthreads();
  for (int i = t; i < n; i += 256) sedge[r0 + i] = sorted[i];
}

// ---------------- GEMM2: h3[NN][NC] bf16 = h2[NN][NH] bf16 @ W2 ----------------
__global__ __launch_bounds__(256) void k_gemm2(const unsigned short* __restrict__ h2,
                                               const unsigned short* __restrict__ W2t,
                                               unsigned short* __restrict__ h3) {
  __shared__ __align__(16) unsigned short As[256][72];
  __shared__ __align__(16) unsigned short Bs[64][72];
  int t = threadIdx.x;
  int rowBase = blockIdx.x * 256;
  int wave = t >> 6, lane = t & 63;
  int wm = wave * 64;
  int lrow = lane & 15, quad = lane >> 4;

  f32x4 acc[4][4];
#pragma unroll
  for (int i = 0; i < 4; ++i)
#pragma unroll
    for (int j = 0; j < 4; ++j) acc[i][j] = (f32x4){0.f, 0.f, 0.f, 0.f};

  for (int k0 = 0; k0 < NH; k0 += 64) {
#pragma unroll
    for (int i = 0; i < 16; ++i) {          // stage A: 256x64 bf16
      int idx = t + i * 256;
      int r = idx >> 4, c4 = idx & 15;
      int row = rowBase + r; if (row >= NN) row = NN - 1;
      *(ushort4*)(&As[r][c4 * 4]) = *(const ushort4*)(h2 + (size_t)row * NH + k0 + c4 * 4);
    }
#pragma unroll
    for (int i = 0; i < 4; ++i) {           // stage B: 64x64 bf16
      int idx = t + i * 256;
      int n = idx >> 4, c4 = idx & 15;
      *(ushort4*)(&Bs[n][c4 * 4]) = *(const ushort4*)(W2t + n * NH + k0 + c4 * 4);
    }
    __syncthreads();
#pragma unroll
    for (int ks = 0; ks < 64; ks += 32) {
      bf16x8 a[4], b[4];
#pragma unroll
      for (int mt = 0; mt < 4; ++mt) a[mt] = *(const bf16x8*)(&As[wm + mt * 16 + lrow][ks + quad * 8]);
#pragma unroll
      for (int nt = 0; nt < 4; ++nt) b[nt] = *(const bf16x8*)(&Bs[nt * 16 + lrow][ks + quad * 8]);
#pragma unroll
      for (int mt = 0; mt < 4; ++mt)
#pragma unroll
        for (int nt = 0; nt < 4; ++nt)
          acc[mt][nt] = __builtin_amdgcn_mfma_f32_16x16x32_bf16(a[mt], b[nt], acc[mt][nt], 0, 0, 0);
    }
    __syncthreads();
  }
#pragma unroll
  for (int mt = 0; mt < 4; ++mt)
#pragma unroll
    for (int nt = 0; nt < 4; ++nt)
#pragma unroll
      for (int r = 0; r < 4; ++r) {
        int row = rowBase + wm + mt * 16 + quad * 4 + r;
        if (row < NN) {
          int col = nt * 16 + lrow;
          h3[(size_t)row * NC + col] = f2bf(acc[mt][nt][r]);
        }
      }
}

// ---------------- propagate 1: h2 = relu(seg_sum(w * h[src]) + b1), D=128 ----------------
__global__ __launch_bounds__(256) void k_prop1(const int* __restrict__ rowptr,
                                               const int2* __restrict__ sedge,
                                               const unsigned short* __restrict__ h,
                                               const float4* __restrict__ b1v,
                                               unsigned short* __restrict__ h2) {
  __shared__ int2 se[4][64];
  int w = threadIdx.x >> 6, lane = threadIdx.x & 63;
  int half = lane >> 5, l2 = lane & 31;
  int node = blockIdx.x * 4 + w;
  int e0 = rowptr[node], e1 = rowptr[node + 1];
  float a0 = 0.f, a1 = 0.f, a2 = 0.f, a3 = 0.f;
  for (int e = e0; e < e1; e += 64) {
    int cnt = e1 - e; if (cnt > 64) cnt = 64;
    if (lane < cnt) se[w][lane] = sedge[e + lane];
    asm volatile("s_waitcnt lgkmcnt(0)" ::: "memory");
    for (int j = 0; j < cnt; j += 2) {
      int idx = j + half;
      int2 ed = (idx < cnt) ? se[w][idx] : make_int2(0, 0);
      float wj = __int_as_float(ed.y);
      uint2 hv = *(const uint2*)(h + (size_t)ed.x * NH + l2 * 4);
      a0 += wj * bf2f((unsigned short)(hv.x & 0xffffu));
      a1 += wj * bf2f((unsigned short)(hv.x >> 16));
      a2 += wj * bf2f((unsigned short)(hv.y & 0xffffu));
      a3 += wj * bf2f((unsigned short)(hv.y >> 16));
    }
  }
  a0 += __shfl_xor(a0, 32); a1 += __shfl_xor(a1, 32);
  a2 += __shfl_xor(a2, 32); a3 += __shfl_xor(a3, 32);
  if (half == 0) {
    float4 b = b1v[l2];
    float o0 = fmaxf(a0 + b.x, 0.f), o1 = fmaxf(a1 + b.y, 0.f);
    float o2 = fmaxf(a2 + b.z, 0.f), o3 = fmaxf(a3 + b.w, 0.f);
    uint2 p;
    p.x = ((unsigned int)f2bf(o1) << 16) | (unsigned int)f2bf(o0);
    p.y = ((unsigned int)f2bf(o3) << 16) | (unsigned int)f2bf(o2);
    *(uint2*)(h2 + (size_t)node * NH + l2 * 4) = p;
  }
}

// ---------------- propagate 2: out = seg_sum(w * h3[src]) + b2, D=64 ----------------
__global__ __launch_bounds__(256) void k_prop2(const int* __restrict__ rowptr,
                                               const int2* __restrict__ sedge,
                                               const unsigned short* __restrict__ h3,
                                               const float4* __restrict__ b2v,
                                               float* __restrict__ out) {
  __shared__ int2 se[4][64];
  int w = threadIdx.x >> 6, lane = threadIdx.x & 63;
  int q = lane >> 4, l4 = lane & 15;
  int node = blockIdx.x * 4 + w;
  int e0 = rowptr[node], e1 = rowptr[node + 1];
  float a0 = 0.f, a1 = 0.f, a2 = 0.f, a3 = 0.f;
  for (int e = e0; e < e1; e += 64) {
    int cnt = e1 - e; if (cnt > 64) cnt = 64;
    if (lane < cnt) se[w][lane] = sedge[e + lane];
    asm volatile("s_waitcnt lgkmcnt(0)" ::: "memory");
    for (int j = 0; j < cnt; j += 4) {
      int idx = j + q;
      int2 ed = (idx < cnt) ? se[w][idx] : make_int2(0, 0);
      float wj = __int_as_float(ed.y);
      uint2 hv = *(const uint2*)(h3 + (size_t)ed.x * NC + l4 * 4);
      a0 += wj * bf2f((unsigned short)(hv.x & 0xffffu));
      a1 += wj * bf2f((unsigned short)(hv.x >> 16));
      a2 += wj * bf2f((unsigned short)(hv.y & 0xffffu));
      a3 += wj * bf2f((unsigned short)(hv.y >> 16));
    }
  }
  a0 += __shfl_xor(a0, 16); a1 += __shfl_xor(a1, 16);
  a2 += __shfl_xor(a2, 16); a3 += __shfl_xor(a3, 16);
  a0 += __shfl_xor(a0, 32); a1 += __shfl_xor(a1, 32);
  a2 += __shfl_xor(a2, 32); a3 += __shfl_xor(a3, 32);
  if (q == 0) {
    float4 b = b2v[l4];
    float4 o = make_float4(a0 + b.x, a1 + b.y, a2 + b.z, a3 + b.w);
    *(float4*)(out + (size_t)node * NC + l4 * 4) = o;
  }
}

extern "C" void kernel_launch(void* const* d_in, const int* in_sizes, int n_in,
                              void* d_out, int out_size, void* d_ws, size_t ws_size,
                              hipStream_t stream) {
  const float* x = (const float*)d_in[0];
  const int* ei = (const int*)d_in[1];   // int32 on device (harness convention)
  const float* ew = (const float*)d_in[2];
  const float* W1 = (const float*)d_in[3];
  const float* b1 = (const float*)d_in[4];
  const float* W2 = (const float*)d_in[5];
  const float* b2 = (const float*)d_in[6];
  float* out = (float*)d_out;

  char* ws = (char*)d_ws;
  size_t off = 0;
  auto alloc = [&](size_t bytes) {
    char* p = ws + off;
    off = (off + bytes + 255) & ~(size_t)255;
    return p;
  };
  unsigned short* W1t = (unsigned short*)alloc((size_t)NF * NH * 2);
  unsigned short* W2t = (unsigned short*)alloc((size_t)NH * NC * 2);
  unsigned short* h   = (unsigned short*)alloc((size_t)NN * NH * 2);
  unsigned short* h2  = (unsigned short*)alloc((size_t)NN * NH * 2);
  unsigned short* h3  = h;  // h dead after prop1; alias to save ws
  int* rowptr     = (int*)alloc((size_t)(NN + 1) * 4);
  int* partTotals = (int*)alloc((NPART + 1) * 4);
  int* partStart  = (int*)alloc((NPART + 1) * 4);
  int* partCursor = (int*)alloc((NPART + 1) * 4);
  int2* sedge     = (int2*)alloc((size_t)NE * 8);
  int2* tmp       = (int2*)alloc((size_t)NE * 8);

  k_zero0<<<4, 256, 0, stream>>>(partTotals);
  k_hist_conv<<<NBH + CONVB, 256, 0, stream>>>(ei, partTotals, W1, W2, W1t, W2t);
  k_pscan<<<1, 1024, 0, stream>>>(partTotals, partStart, partCursor, rowptr);
  k_part_gemm1<<<NBP + 782, 256, 0, stream>>>(ei, ew, partCursor, tmp, x, W1t, h);
  k_sortp<<<NPART, 256, 0, stream>>>(partStart, tmp, sedge, rowptr);
  k_prop1<<<NN / 4, 256, 0, stream>>>(rowptr, sedge, h, (const float4*)b1, h2);
  k_gemm2<<<(NN + 255) / 256, 256, 0, stream>>>(h2, W2t, h3);
  k_prop2<<<NN / 4, 256, 0, stream>>>(rowptr, sedge, h3, (const float4*)b2, out);
}